// Round 8
// baseline (306.789 us; speedup 1.0000x reference)
//
#include <hip/hip_runtime.h>
#include <math.h>

#define NQ 12
#define DIM 4096
#define NGATES 36
#define NROUND 9

typedef float f32x4 __attribute__((ext_vector_type(4)));
typedef __fp16 fp16x2 __attribute__((ext_vector_type(2)));
typedef __fp16 fp16x4 __attribute__((ext_vector_type(4)));
typedef __fp16 fp16x8 __attribute__((ext_vector_type(8)));

// GF(2)-linear LDS swizzle (bijective on 12 bits): sw(a^b) = sw(a)^sw(b)
constexpr unsigned swz(unsigned x) { return x ^ (x >> 4); }

// ---- compile-time circuit plan: CNOTs folded into GF(2) index maps ----
// Gate on logical bit b: pair mask m = M*e_b, "1"-selector = row b of M^-1.
// 4 gates per round; round = dense 16x16 complex matrix on the 4-bit slot
// subspace, applied to 256 cosets via MFMA (K=32 re/im-interleaved).
struct Round {
  unsigned s[4];       // selectors of the 4 gates
  unsigned l[4];       // sorted pivot low-masks for 4-zero-bit insertion
  unsigned cbsw8[16];  // swizzled byte offsets of the 16 coset slots
  unsigned dt[4];      // base8 XOR-delta for coset c ^= tt*16 (tile step)
};
struct PlanT {
  Round rd[NROUND];
  unsigned zsel[NQ];
};

constexpr PlanT make_plan() {
  PlanT P{};
  unsigned Mcol[NQ] = {}, Minv[NQ] = {};
  for (int i = 0; i < NQ; ++i) { Mcol[i] = 1u << i; Minv[i] = 1u << i; }
  unsigned gm[NGATES] = {}, gs[NGATES] = {};
  int g = 0;
  for (int L = 0; L < 3; ++L) {
    for (int q = 0; q < NQ; ++q) { int b = NQ - 1 - q; gm[g] = Mcol[b]; gs[g] = Minv[b]; ++g; }
    for (int q = 0; q < NQ; ++q) {
      int bc = NQ - 1 - q, bt = NQ - 1 - ((q + 1) % NQ);
      Mcol[bc] ^= Mcol[bt];
      Minv[bt] ^= Minv[bc];
    }
  }
  for (int r = 0; r < NROUND; ++r) {
    unsigned m[4], red[4];
    for (int k = 0; k < 4; ++k) { m[k] = gm[4*r+k]; red[k] = m[k]; P.rd[r].s[k] = gs[4*r+k]; }
    for (int a = 0; a < 4; ++a) {
      unsigned p = red[a] & (0u - red[a]);
      for (int b = a + 1; b < 4; ++b) if (red[b] & p) red[b] ^= red[a];
    }
    unsigned piv[4];
    for (int a = 0; a < 4; ++a) piv[a] = red[a] & (0u - red[a]);
    for (int a = 0; a < 4; ++a)
      for (int b = a + 1; b < 4; ++b)
        if (piv[a] > piv[b]) { unsigned tp = piv[a]; piv[a] = piv[b]; piv[b] = tp; }
    for (int a = 0; a < 4; ++a) P.rd[r].l[a] = piv[a] - 1u;
    for (int d = 0; d < 16; ++d) {
      unsigned c = 0;
      for (int k = 0; k < 4; ++k) if (d & (1 << k)) c ^= m[k];
      P.rd[r].cbsw8[d] = swz(c) << 3;
    }
    // tile deltas: full base8-linear image of coset step tt*16
    for (int tt = 0; tt < 4; ++tt) {
      unsigned c = (unsigned)tt << 4;
      unsigned j = c;
      j = ((j & ~P.rd[r].l[0]) << 1) | (j & P.rd[r].l[0]);
      j = ((j & ~P.rd[r].l[1]) << 1) | (j & P.rd[r].l[1]);
      j = ((j & ~P.rd[r].l[2]) << 1) | (j & P.rd[r].l[2]);
      j = ((j & ~P.rd[r].l[3]) << 1) | (j & P.rd[r].l[3]);
      unsigned d = swz(j) << 3;
      for (int k = 0; k < 4; ++k)
        if (__builtin_popcount(j & P.rd[r].s[k]) & 1) d ^= P.rd[r].cbsw8[1u << k];
      P.rd[r].dt[tt] = d;
    }
  }
  for (int q = 0; q < NQ; ++q) P.zsel[q] = Minv[NQ - 1 - q];
  return P;
}

constexpr PlanT PLAN = make_plan();

// ---- prep: per round build the dense 16x16 complex tensor-product matrix,
// emit 4 fp16 A-operand matrices [16 rows s][32 k] row-major:
//   Are: [s][2j]=Re U[s][j], [s][2j+1]=-Im U[s][j]   (hi and lo split)
//   Aim: [s][2j]=Im U[s][j], [s][2j+1]= Re U[s][j]
// layout: amat + r*2048 + matid*512 + s*32 + k  (halves); matid 0..3 =
// Are_hi, Are_lo, Aim_hi, Aim_lo. 16B-aligned fragments.
__global__ void qc_prep(const float* __restrict__ params, __fp16* __restrict__ amat) {
  int t = threadIdx.x;             // 256 threads; 144 used
  int r = t >> 4, s = t & 15;
  if (r >= NROUND) return;
  float U[4][8];
  for (int k = 0; k < 4; ++k) {
    int gg = r * 4 + k;
    float h1 = params[3*gg+0]*0.5f, hh2 = params[3*gg+1]*0.5f, h3 = params[3*gg+2]*0.5f;
    float c1 = cosf(h1), s1 = sinf(h1);
    float c2 = cosf(hh2), s2 = sinf(hh2);
    float c3 = cosf(h3), s3 = sinf(h3);
    float a00r =  c2*c1, a00i =  s2*s1;
    float a01r = -s2*c1, a01i = -c2*s1;
    float a10r =  s2*c1, a10i = -c2*s1;
    float a11r =  c2*c1, a11i = -s2*s1;
    U[k][0] = c3*a00r + s3*a00i;  U[k][1] = c3*a00i - s3*a00r;
    U[k][2] = c3*a01r + s3*a01i;  U[k][3] = c3*a01i - s3*a01r;
    U[k][4] = c3*a10r - s3*a10i;  U[k][5] = c3*a10i + s3*a10r;
    U[k][6] = c3*a11r - s3*a11i;  U[k][7] = c3*a11i + s3*a11r;
  }
  __fp16* b0 = amat + r*2048 + s*32;   // Are_hi row
  __fp16* b1 = b0 + 512;               // Are_lo
  __fp16* b2 = b0 + 1024;              // Aim_hi
  __fp16* b3 = b0 + 1536;              // Aim_lo
  for (int j = 0; j < 16; ++j) {
    float pr = 1.f, pi = 0.f;
    for (int k = 0; k < 4; ++k) {
      int idx = ((((s >> k) & 1) * 2) + ((j >> k) & 1)) * 2;
      float gr = U[k][idx], gi = U[k][idx + 1];
      float npr = pr * gr - pi * gi;
      pi = pr * gi + pi * gr;
      pr = npr;
    }
    float v0_ =  pr; __fp16 e0 = (__fp16)v0_;
    float v1_ = -pi; __fp16 e1 = (__fp16)v1_;
    float v2_ =  pi; __fp16 e2 = (__fp16)v2_;
    float v3_ =  pr; __fp16 e3 = (__fp16)v3_;
    b0[2*j]   = e0;  b1[2*j]   = (__fp16)(v0_ - (float)e0);
    b0[2*j+1] = e1;  b1[2*j+1] = (__fp16)(v1_ - (float)e1);
    b2[2*j]   = e2;  b3[2*j]   = (__fp16)(v2_ - (float)e2);
    b2[2*j+1] = e3;  b3[2*j+1] = (__fp16)(v3_ - (float)e3);
  }
}

__global__ __launch_bounds__(256)
__attribute__((amdgpu_waves_per_eu(4, 5)))
void qc_main(const float* __restrict__ x, const __fp16* __restrict__ amat,
             float* __restrict__ out) {
  __shared__ float2 sst[DIM];        // 32768 B
  char* sb = (char*)sst;
  const int t = threadIdx.x;
  const long row = blockIdx.x;

  // ---- stage x row (im=0), accumulate sum of squares ----
  const float4* x4 = (const float4*)(x + (size_t)row * DIM);
  float ssq = 0.f;
#pragma unroll
  for (int k = 0; k < 4; ++k) {
    float4 a = x4[t + 256*k];
    int j0 = 4*(t + 256*k);
    *(float2*)(sb + (swz((unsigned)j0)     << 3)) = make_float2(a.x, 0.f);
    *(float2*)(sb + (swz((unsigned)(j0+1)) << 3)) = make_float2(a.y, 0.f);
    *(float2*)(sb + (swz((unsigned)(j0+2)) << 3)) = make_float2(a.z, 0.f);
    *(float2*)(sb + (swz((unsigned)(j0+3)) << 3)) = make_float2(a.w, 0.f);
    ssq += a.x*a.x + a.y*a.y + a.z*a.z + a.w*a.w;
  }
#pragma unroll
  for (int off = 32; off > 0; off >>= 1) ssq += __shfl_down(ssq, off, 64);
  __syncthreads();

  // ---- 9 rounds; each round = dense 16x16 complex gate-product via MFMA.
  // Wave w handles tiles 4w+tt (16 cosets each). Lane l: coset col = l&15,
  // slots 4q..4q+3 with q = l>>4 (A/B K-fragment AND C/D row mapping agree,
  // so per-lane read-set == write-set; no intra-round barrier needed).
  // PHASE-SPLIT round body: all reads -> all converts -> all MFMA -> all
  // writes. Alias conservatism (char* LDS) forbids sinking stores above
  // loads, so the read burst / MFMA burst structure is codegen-guaranteed.
#pragma unroll 1
  for (int r = 0; r < NROUND; ++r) {
    const unsigned s0 = PLAN.rd[r].s[0], sA = PLAN.rd[r].s[1];
    const unsigned sB = PLAN.rd[r].s[2], sC = PLAN.rd[r].s[3];
    const unsigned l0 = PLAN.rd[r].l[0], l1 = PLAN.rd[r].l[1];
    const unsigned l2 = PLAN.rd[r].l[2], l3 = PLAN.rd[r].l[3];
    const unsigned CB1 = PLAN.rd[r].cbsw8[1], CB2 = PLAN.rd[r].cbsw8[2];
    const unsigned CB3 = PLAN.rd[r].cbsw8[3];
    const unsigned C4 = PLAN.rd[r].cbsw8[4], C8 = PLAN.rd[r].cbsw8[8];
    const unsigned dts[4] = {0u, PLAN.rd[r].dt[1], PLAN.rd[r].dt[2], PLAN.rd[r].dt[3]};

    // coset for tile 0: c0 = wave*64 + (lane&15)
    unsigned j = ((unsigned)t & 0xC0u) | ((unsigned)t & 15u);
    j = ((j & ~l0) << 1) | (j & l0);
    j = ((j & ~l1) << 1) | (j & l1);
    j = ((j & ~l2) << 1) | (j & l2);
    j = ((j & ~l3) << 1) | (j & l3);
    unsigned adj8 = 0;
    adj8 ^= (unsigned)(-(int)(__popc(j & s0) & 1)) & CB1;
    adj8 ^= (unsigned)(-(int)(__popc(j & sA) & 1)) & CB2;
    adj8 ^= (unsigned)(-(int)(__popc(j & sB) & 1)) & C4;
    adj8 ^= (unsigned)(-(int)(__popc(j & sC) & 1)) & C8;
    const unsigned q = ((unsigned)t >> 4) & 3u;
    const unsigned qsel = ((q & 1u) ? C4 : 0u) ^ ((q & 2u) ? C8 : 0u);
    const unsigned b0a = (((j ^ (j >> 4)) << 3) ^ adj8) ^ qsel;

    // A-operand fragments (uniform-ish global loads; L1/L2 resident)
    const fp16x8* am = (const fp16x8*)(amat + (size_t)r * 2048);
    const int fo = (t & 15) * 4 + (int)q;
    const fp16x8 Arh = am[fo];
    const fp16x8 Arl = am[64 + fo];
    const fp16x8 Aih = am[128 + fo];
    const fp16x8 Ail = am[192 + fo];

    // ---- phase 1: all 16 ds_reads ----
    unsigned ad[4];
    float2 A[4][4];
#pragma unroll
    for (int tt = 0; tt < 4; ++tt) {
      const unsigned bb = b0a ^ dts[tt];
      ad[tt] = bb;
      A[tt][0] = *(const float2*)(sb + bb);
      A[tt][1] = *(const float2*)(sb + (bb ^ CB1));
      A[tt][2] = *(const float2*)(sb + (bb ^ CB2));
      A[tt][3] = *(const float2*)(sb + (bb ^ CB3));
    }

    // ---- phase 2: all converts to fp16 hi/lo B-fragments ----
    fp16x8 Bhi[4], Blo[4];
#pragma unroll
    for (int tt = 0; tt < 4; ++tt) {
      fp16x2 p0 = __builtin_amdgcn_cvt_pkrtz(A[tt][0].x, A[tt][0].y);
      fp16x2 p1 = __builtin_amdgcn_cvt_pkrtz(A[tt][1].x, A[tt][1].y);
      fp16x2 p2 = __builtin_amdgcn_cvt_pkrtz(A[tt][2].x, A[tt][2].y);
      fp16x2 p3 = __builtin_amdgcn_cvt_pkrtz(A[tt][3].x, A[tt][3].y);
      fp16x2 q0 = __builtin_amdgcn_cvt_pkrtz(A[tt][0].x - (float)p0[0], A[tt][0].y - (float)p0[1]);
      fp16x2 q1 = __builtin_amdgcn_cvt_pkrtz(A[tt][1].x - (float)p1[0], A[tt][1].y - (float)p1[1]);
      fp16x2 q2 = __builtin_amdgcn_cvt_pkrtz(A[tt][2].x - (float)p2[0], A[tt][2].y - (float)p2[1]);
      fp16x2 q3 = __builtin_amdgcn_cvt_pkrtz(A[tt][3].x - (float)p3[0], A[tt][3].y - (float)p3[1]);
      fp16x4 u01 = __builtin_shufflevector(p0, p1, 0, 1, 2, 3);
      fp16x4 u23 = __builtin_shufflevector(p2, p3, 0, 1, 2, 3);
      Bhi[tt] = __builtin_shufflevector(u01, u23, 0, 1, 2, 3, 4, 5, 6, 7);
      fp16x4 w01 = __builtin_shufflevector(q0, q1, 0, 1, 2, 3);
      fp16x4 w23 = __builtin_shufflevector(q2, q3, 0, 1, 2, 3);
      Blo[tt] = __builtin_shufflevector(w01, w23, 0, 1, 2, 3, 4, 5, 6, 7);
    }

    // ---- phase 3: 24 MFMAs, 8 independent accumulator chains ----
    f32x4 are[4], aim[4];
#pragma unroll
    for (int tt = 0; tt < 4; ++tt) {
      are[tt] = (f32x4){0.f, 0.f, 0.f, 0.f};
      aim[tt] = (f32x4){0.f, 0.f, 0.f, 0.f};
      are[tt] = __builtin_amdgcn_mfma_f32_16x16x32_f16(Arh, Bhi[tt], are[tt], 0, 0, 0);
      aim[tt] = __builtin_amdgcn_mfma_f32_16x16x32_f16(Aih, Bhi[tt], aim[tt], 0, 0, 0);
      are[tt] = __builtin_amdgcn_mfma_f32_16x16x32_f16(Arl, Bhi[tt], are[tt], 0, 0, 0);
      aim[tt] = __builtin_amdgcn_mfma_f32_16x16x32_f16(Ail, Bhi[tt], aim[tt], 0, 0, 0);
      are[tt] = __builtin_amdgcn_mfma_f32_16x16x32_f16(Arh, Blo[tt], are[tt], 0, 0, 0);
      aim[tt] = __builtin_amdgcn_mfma_f32_16x16x32_f16(Aih, Blo[tt], aim[tt], 0, 0, 0);
    }

    // ---- phase 4: all 16 ds_writes ----
    // C/D layout: col = lane&15 (coset), row = q*4+reg (slot) -> same addrs
#pragma unroll
    for (int tt = 0; tt < 4; ++tt) {
      *(float2*)(sb + ad[tt])         = make_float2(are[tt][0], aim[tt][0]);
      *(float2*)(sb + (ad[tt] ^ CB1)) = make_float2(are[tt][1], aim[tt][1]);
      *(float2*)(sb + (ad[tt] ^ CB2)) = make_float2(are[tt][2], aim[tt][2]);
      *(float2*)(sb + (ad[tt] ^ CB3)) = make_float2(are[tt][3], aim[tt][3]);
    }
    __syncthreads();
  }

  // ---- measurement: 16 consecutive amps/thread, WHT over low 4 bits ----
  const unsigned mbase8 = (((16u * (unsigned)t) ^ (unsigned)t) << 3);
  float p[16];
#pragma unroll
  for (int c = 0; c < 16; ++c) {
    float2 v = *(const float2*)(sb + (mbase8 ^ ((unsigned)c << 3)));
    p[c] = v.x * v.x + v.y * v.y;
  }
#pragma unroll
  for (int b = 0; b < 4; ++b) {
#pragma unroll
    for (int c = 0; c < 16; ++c) {
      if (!(c & (1 << b))) {
        const int c1 = c | (1 << b);
        float u = p[c], v = p[c1];
        p[c] = u + v; p[c1] = u - v;
      }
    }
  }
  float zs[NQ];
#pragma unroll
  for (int qq = 0; qq < NQ; ++qq) {
    const unsigned m = PLAN.zsel[qq];
    const float v = p[m & 15u];
    const int sgn = __popc((unsigned)t & (m >> 4)) & 1;
    zs[qq] = sgn ? -v : v;
  }

  // ---- block reduction via LDS (replaces 72-bpermute shfl tree) ----
  // layout: 6 float2 columns of 256 entries at k*2048; ssq at 12288;
  // partials at 12352.
  __syncthreads();               // all state reads done; safe to overwrite
#pragma unroll
  for (int k = 0; k < 6; ++k)
    *(float2*)(sb + (((unsigned)(k << 8) + (unsigned)t) << 3)) =
        make_float2(zs[2*k], zs[2*k+1]);
  if ((t & 63) == 0) *(float*)(sb + 12288 + (t >> 6) * 4) = ssq;
  __syncthreads();
  if (t < 192) {
    const int k = t >> 5, j = t & 31;
    const char* cbp = sb + (k << 11) + (j << 3);
    float2 acc = *(const float2*)(cbp);
#pragma unroll
    for (int i = 1; i < 8; ++i) {         // stride 32 entries: conflict-free
      float2 vv = *(const float2*)(cbp + i * 256);
      acc.x += vv.x; acc.y += vv.y;
    }
#pragma unroll
    for (int off = 16; off > 0; off >>= 1) {
      acc.x += __shfl_down(acc.x, off, 32);
      acc.y += __shfl_down(acc.y, off, 32);
    }
    if (j == 0) *(float2*)(sb + 12352 + (k << 3)) = acc;
  }
  __syncthreads();
  if (t < NQ) {
    const float* sq = (const float*)(sb + 12288);
    const float den = sq[0] + sq[1] + sq[2] + sq[3];
    out[row * NQ + t] = ((const float*)(sb + 12352))[t] / den;
  }
}

extern "C" void kernel_launch(void* const* d_in, const int* in_sizes, int n_in,
                              void* d_out, int out_size, void* d_ws, size_t ws_size,
                              hipStream_t stream) {
  const float* x = (const float*)d_in[0];
  const float* params = (const float*)d_in[1];
  float* out = (float*)d_out;
  __fp16* amat = (__fp16*)d_ws;                // 9 rounds * 4 mats * 16x32 fp16
  const int nrows = in_sizes[0] / DIM;         // 8192
  qc_prep<<<dim3(1), dim3(256), 0, stream>>>(params, amat);
  qc_main<<<dim3(nrows), dim3(256), 0, stream>>>(x, amat, out);
}